// Round 1
// baseline (939.718 us; speedup 1.0000x reference)
//
#include <hip/hip_runtime.h>

// CRF loss: out[b] = logZ[b] - target[b]
// B=256, S=2048, D=64.  One wave per batch for the serial scan.

#define B_ 256
#define S_ 2048
#define D_ 64

// ---------------- target scores: point + transition ----------------
__global__ __launch_bounds__(256) void target_kernel(
    const float* __restrict__ y_pred, const int* __restrict__ y_true,
    const float* __restrict__ mask, const float* __restrict__ trans,
    float* __restrict__ target)
{
    int b = blockIdx.x;
    int tid = threadIdx.x;
    const int*   yt = y_true + (size_t)b * S_;
    const float* mk = mask   + (size_t)b * S_;
    const float* yp = y_pred + (size_t)b * S_ * D_;

    float acc = 0.f;
    for (int n = tid; n < S_; n += 256) {
        int   tn = yt[n];
        float mn = mk[n];
        // point score: (m*y_pred) . (m*onehot) = m^2 * y_pred[n, t_n]
        acc += mn * mn * yp[(size_t)n * D_ + tn];
        // transition score: m_n * m_{n+1} * trans[t_n, t_{n+1}]
        if (n + 1 < S_) {
            int   tn1 = yt[n + 1];
            float mn1 = mk[n + 1];
            acc += mn * mn1 * trans[tn * D_ + tn1];
        }
    }
    #pragma unroll
    for (int m = 32; m >= 1; m >>= 1) acc += __shfl_xor(acc, m, 64);
    __shared__ float sred[4];
    int wid = tid >> 6;
    if ((tid & 63) == 0) sred[wid] = acc;
    __syncthreads();
    if (tid == 0) target[b] = sred[0] + sred[1] + sred[2] + sred[3];
}

// ---------------- forward-algorithm scan (one wave per batch) ----------------
__global__ __launch_bounds__(64) void scan_kernel(
    const float* __restrict__ y_pred, const float* __restrict__ mask,
    const float* __restrict__ trans, const float* __restrict__ target,
    float* __restrict__ out)
{
    const int b = blockIdx.x;
    const int j = threadIdx.x;              // lane = state index j (0..63)
    const float* yprow = y_pred + (size_t)b * S_ * D_;
    const float* mrow  = mask   + (size_t)b * S_;

    // ET column j in registers: et[i] = exp(trans[i][j])  (loop-invariant)
    float et[D_];
    #pragma unroll
    for (int i = 0; i < D_; ++i) et[i] = __expf(trans[i * D_ + j]);

    // double-buffered broadcast of p (exp-domain state)
    __shared__ float4 sp4[2][D_ / 4];

    // state0 = y_pred[b,0,:] * m0 ;  p = exp(state0), offset O = 0
    float m0 = mrow[0];
    float p  = __expf(yprow[j] * m0);
    float O  = 0.f;
    ((float*)sp4[0])[j] = p;

    // prefetch e, cm for t = 1..4 (depth-4: ~1200cy slack vs ~900cy HBM latency)
    float e0 = yprow[(size_t)1 * D_ + j], e1 = yprow[(size_t)2 * D_ + j];
    float e2 = yprow[(size_t)3 * D_ + j], e3 = yprow[(size_t)4 * D_ + j];
    float c0 = mrow[1], c1 = mrow[2], c2 = mrow[3], c3 = mrow[4];
    __syncthreads();

    auto step = [&](int t, int bufr, float ecur, float cmcur,
                    float& enext, float& cnext) {
        // prefetch t+4 (clamped; unused tail values are harmless)
        int tn = t + 4; if (tn > S_ - 1) tn = S_ - 1;
        float tmpe = yprow[(size_t)tn * D_ + j];
        float tmpc = mrow[tn];

        // matvec: sum_j = sum_i p_i * ET[i][j]   (broadcast LDS reads, 4 accums)
        const float4* pb = sp4[bufr];
        float a0 = 0.f, a1 = 0.f, a2 = 0.f, a3 = 0.f;
        #pragma unroll
        for (int c = 0; c < 16; ++c) {
            float4 pv = pb[c];
            a0 = fmaf(pv.x, et[4 * c + 0], a0);
            a1 = fmaf(pv.y, et[4 * c + 1], a1);
            a2 = fmaf(pv.z, et[4 * c + 2], a2);
            a3 = fmaf(pv.w, et[4 * c + 3], a3);
        }
        float sum = (a0 + a1) + (a2 + a3);

        // S_p = sum_i p_i  — depends only on previous p, overlaps the matvec
        float sp_ = p;
        #pragma unroll
        for (int m = 1; m <= 32; m <<= 1) sp_ += __shfl_xor(sp_, m, 64);

        if (cmcur == 1.0f) {
            // fast path: p' = (sum / S_p) * exp(e);  O += log(S_p)
            float rcp = __builtin_amdgcn_rcpf(sp_);
            p = sum * rcp * __expf(ecur);
            O += __logf(sp_);
        } else {
            // general masked path (log-domain blend, exact renormalization)
            float outn = __logf(sum) + ecur * cmcur;   // (out - O)
            float sj   = __logf(p);                    // (state - O)
            float ns   = cmcur * outn + (1.f - cmcur) * sj;
            float M = ns;
            #pragma unroll
            for (int m = 1; m <= 32; m <<= 1) M = fmaxf(M, __shfl_xor(M, m, 64));
            p = __expf(ns - M);
            O += M;
        }

        ((float*)sp4[bufr ^ 1])[j] = p;
        __syncthreads();
        enext = tmpe; cnext = tmpc;
    };

    // steps t = 1 .. 2044, unrolled x4 (static LDS buffer + register rotation)
    int t = 1;
    for (; t + 3 <= S_ - 1; t += 4) {
        step(t + 0, 0, e0, c0, e0, c0);
        step(t + 1, 1, e1, c1, e1, c1);
        step(t + 2, 0, e2, c2, e2, c2);
        step(t + 3, 1, e3, c3, e3, c3);
    }
    // remainder t = 2045, 2046, 2047 (prefetched values already in e0..e2)
    step(2045, 0, e0, c0, e0, c0);
    step(2046, 1, e1, c1, e1, c1);
    step(2047, 0, e2, c2, e2, c2);

    // logZ = O + log(sum_j p_j);  out = logZ - target
    float fs = p;
    #pragma unroll
    for (int m = 1; m <= 32; m <<= 1) fs += __shfl_xor(fs, m, 64);
    if (j == 0) out[b] = O + __logf(fs) - target[b];
}

extern "C" void kernel_launch(void* const* d_in, const int* in_sizes, int n_in,
                              void* d_out, int out_size, void* d_ws, size_t ws_size,
                              hipStream_t stream)
{
    const float* y_pred = (const float*)d_in[0];
    const int*   y_true = (const int*)d_in[1];
    const float* mask   = (const float*)d_in[2];
    const float* trans  = (const float*)d_in[3];
    float* outp   = (float*)d_out;
    float* target = (float*)d_ws;   // 256 floats of scratch

    hipLaunchKernelGGL(target_kernel, dim3(B_), dim3(256), 0, stream,
                       y_pred, y_true, mask, trans, target);
    hipLaunchKernelGGL(scan_kernel, dim3(B_), dim3(64), 0, stream,
                       y_pred, mask, trans, target, outp);
}

// Round 2
// 628.557 us; speedup vs baseline: 1.4950x; 1.4950x over previous
//
#include <hip/hip_runtime.h>

// CRF loss: out[b] = logZ[b] - target[b]
// B=256, S=2048, D=64.  One wave per batch for the serial scan.
// Round 2: barrier-free scan loop (single-wave WG => in-order DS pipe),
//          normalization every 4 steps, packed-f32 (v_pk_fma_f32) matvec.

#define B_ 256
#define S_ 2048
#define D_ 64

typedef float f32x2 __attribute__((ext_vector_type(2)));

static __device__ __forceinline__ f32x2 mk2(float a, float b) {
    f32x2 r; r.x = a; r.y = b; return r;
}

// ---------------- target scores: point + transition ----------------
__global__ __launch_bounds__(256) void target_kernel(
    const float* __restrict__ y_pred, const int* __restrict__ y_true,
    const float* __restrict__ mask, const float* __restrict__ trans,
    float* __restrict__ target)
{
    int b = blockIdx.x;
    int tid = threadIdx.x;
    const int*   yt = y_true + (size_t)b * S_;
    const float* mk = mask   + (size_t)b * S_;
    const float* yp = y_pred + (size_t)b * S_ * D_;

    float acc = 0.f;
    for (int n = tid; n < S_; n += 256) {
        int   tn = yt[n];
        float mn = mk[n];
        acc += mn * mn * yp[(size_t)n * D_ + tn];
        if (n + 1 < S_) {
            int   tn1 = yt[n + 1];
            float mn1 = mk[n + 1];
            acc += mn * mn1 * trans[tn * D_ + tn1];
        }
    }
    #pragma unroll
    for (int m = 32; m >= 1; m >>= 1) acc += __shfl_xor(acc, m, 64);
    __shared__ float sred[4];
    int wid = tid >> 6;
    if ((tid & 63) == 0) sred[wid] = acc;
    __syncthreads();
    if (tid == 0) target[b] = sred[0] + sred[1] + sred[2] + sred[3];
}

// ---------------- forward-algorithm scan (one wave per batch) ----------------
__global__ __launch_bounds__(64) void scan_kernel(
    const float* __restrict__ y_pred, const float* __restrict__ mask,
    const float* __restrict__ trans, const float* __restrict__ target,
    float* __restrict__ out)
{
    const int b = blockIdx.x;
    const int j = threadIdx.x;              // lane = state index j (0..63)
    const float* yprow = y_pred + (size_t)b * S_ * D_;
    const float* mrow  = mask   + (size_t)b * S_;

    // ET column j, packed in pairs: et2[c] = { exp(trans[2c][j]), exp(trans[2c+1][j]) }
    f32x2 et2[D_ / 2];
    #pragma unroll
    for (int c = 0; c < D_ / 2; ++c) {
        et2[c].x = __expf(trans[(2 * c + 0) * D_ + j]);
        et2[c].y = __expf(trans[(2 * c + 1) * D_ + j]);
    }

    // double-buffered broadcast of p (exp-domain state). Single wave per WG:
    // DS pipe is in-order per wave -> NO barriers needed in the loop.
    __shared__ float4 sp4[2][D_ / 4];

    float m0 = mrow[0];
    float p  = __expf(yprow[j] * m0);
    float O  = 0.f;
    ((float*)sp4[0])[j] = p;

    // prefetch e, cm for t = 1..4 (stays in flight across steps: no vmcnt drain)
    float e0 = yprow[(size_t)1 * D_ + j], e1 = yprow[(size_t)2 * D_ + j];
    float e2 = yprow[(size_t)3 * D_ + j], e3 = yprow[(size_t)4 * D_ + j];
    float c0 = mrow[1], c1 = mrow[2], c2 = mrow[3], c3 = mrow[4];

    auto step = [&](int t, int bufr, bool donorm, float ecur, float cmcur,
                    float& enext, float& cnext) {
        // prefetch t+4 (clamped; redundant tail loads are harmless)
        int tn = t + 4; if (tn > S_ - 1) tn = S_ - 1;
        float tmpe = yprow[(size_t)tn * D_ + j];
        float tmpc = mrow[tn];

        // matvec: sum = sum_i p_i * ET[i][j]  (broadcast LDS reads, packed f32)
        const float4* pb = sp4[bufr];
        f32x2 a0 = mk2(0.f, 0.f), a1 = a0, a2 = a0, a3 = a0;
        #pragma unroll
        for (int c = 0; c < 16; c += 2) {
            float4 u = pb[c], v = pb[c + 1];
            a0 = __builtin_elementwise_fma(mk2(u.x, u.y), et2[2 * c + 0], a0);
            a1 = __builtin_elementwise_fma(mk2(u.z, u.w), et2[2 * c + 1], a1);
            a2 = __builtin_elementwise_fma(mk2(v.x, v.y), et2[2 * c + 2], a2);
            a3 = __builtin_elementwise_fma(mk2(v.z, v.w), et2[2 * c + 3], a3);
        }
        f32x2 s = (a0 + a1) + (a2 + a3);
        float sum = s.x + s.y;

        // every-4-steps renormalization factor from PREVIOUS p (off critical path)
        float spn = 0.f;
        if (donorm) {
            float sp_ = p;
            #pragma unroll
            for (int m = 1; m <= 32; m <<= 1) sp_ += __shfl_xor(sp_, m, 64);
            spn = sp_;
        }

        if (cmcur == 1.0f) {
            float scale = __expf(ecur);
            if (donorm) {
                p = sum * __builtin_amdgcn_rcpf(spn) * scale;
                O += __logf(spn);
            } else {
                p = sum * scale;           // deferred normalization
            }
        } else {
            // general masked path (log-domain blend, full renormalization)
            float outn = __logf(sum) + ecur * cmcur;   // (out - O)
            float sj   = __logf(p);                    // (state - O)
            float ns   = cmcur * outn + (1.f - cmcur) * sj;
            float M = ns;
            #pragma unroll
            for (int m = 1; m <= 32; m <<= 1) M = fmaxf(M, __shfl_xor(M, m, 64));
            p = __expf(ns - M);
            O += M;
        }

        ((float*)sp4[bufr ^ 1])[j] = p;     // in-order DS pipe: next read sees it
        enext = tmpe; cnext = tmpc;
    };

    // steps t = 1 .. 2044 in groups of 4 (normalize on the 4th)
    for (int t = 1; t + 3 <= 2044; t += 4) {
        step(t + 0, 0, false, e0, c0, e0, c0);
        step(t + 1, 1, false, e1, c1, e1, c1);
        step(t + 2, 0, false, e2, c2, e2, c2);
        step(t + 3, 1, true,  e3, c3, e3, c3);
    }
    // remainder t = 2045, 2046, 2047 (values already prefetched into e0..e2)
    step(2045, 0, false, e0, c0, e0, c0);
    step(2046, 1, false, e1, c1, e1, c1);
    step(2047, 0, false, e2, c2, e2, c2);

    // logZ = O + log(sum_j p_j);  out = logZ - target
    float fs = p;
    #pragma unroll
    for (int m = 1; m <= 32; m <<= 1) fs += __shfl_xor(fs, m, 64);
    if (j == 0) out[b] = O + __logf(fs) - target[b];
}

extern "C" void kernel_launch(void* const* d_in, const int* in_sizes, int n_in,
                              void* d_out, int out_size, void* d_ws, size_t ws_size,
                              hipStream_t stream)
{
    const float* y_pred = (const float*)d_in[0];
    const int*   y_true = (const int*)d_in[1];
    const float* mask   = (const float*)d_in[2];
    const float* trans  = (const float*)d_in[3];
    float* outp   = (float*)d_out;
    float* target = (float*)d_ws;   // 256 floats of scratch

    hipLaunchKernelGGL(target_kernel, dim3(B_), dim3(256), 0, stream,
                       y_pred, y_true, mask, trans, target);
    hipLaunchKernelGGL(scan_kernel, dim3(B_), dim3(64), 0, stream,
                       y_pred, mask, trans, target, outp);
}

// Round 3
// 542.954 us; speedup vs baseline: 1.7308x; 1.1577x over previous
//
#include <hip/hip_runtime.h>

// CRF loss: out[b] = logZ[b] - target[b].  B=256, S=2048, D=64.
// Round 3: true 8-deep global prefetch (group-pipelined), exact power-of-2
//          renormalization via readfirstlane (no shfl chain on critical path),
//          single LDS broadcast buffer, 8-accumulator packed-f32 matvec.

#define B_ 256
#define S_ 2048
#define D_ 64

typedef float f32x2 __attribute__((ext_vector_type(2)));

static __device__ __forceinline__ f32x2 mk2(float a, float b) {
    f32x2 r; r.x = a; r.y = b; return r;
}

// ---------------- target scores: point + transition ----------------
__global__ __launch_bounds__(256) void target_kernel(
    const float* __restrict__ y_pred, const int* __restrict__ y_true,
    const float* __restrict__ mask, const float* __restrict__ trans,
    float* __restrict__ target)
{
    int b = blockIdx.x;
    int tid = threadIdx.x;
    const int*   yt = y_true + (size_t)b * S_;
    const float* mk = mask   + (size_t)b * S_;
    const float* yp = y_pred + (size_t)b * S_ * D_;

    float acc = 0.f;
    for (int n = tid; n < S_; n += 256) {
        int   tn = yt[n];
        float mn = mk[n];
        acc += mn * mn * yp[(size_t)n * D_ + tn];
        if (n + 1 < S_) {
            int   tn1 = yt[n + 1];
            float mn1 = mk[n + 1];
            acc += mn * mn1 * trans[tn * D_ + tn1];
        }
    }
    #pragma unroll
    for (int m = 32; m >= 1; m >>= 1) acc += __shfl_xor(acc, m, 64);
    __shared__ float sred[4];
    int wid = tid >> 6;
    if ((tid & 63) == 0) sred[wid] = acc;
    __syncthreads();
    if (tid == 0) target[b] = sred[0] + sred[1] + sred[2] + sred[3];
}

// ---------------- forward-algorithm scan (one wave per batch) ----------------
__global__ __launch_bounds__(64) void scan_kernel(
    const float* __restrict__ y_pred, const float* __restrict__ mask,
    const float* __restrict__ trans, const float* __restrict__ target,
    float* __restrict__ out)
{
    const int b = blockIdx.x;
    const int j = threadIdx.x;              // lane = state index j
    const float* yprow = y_pred + (size_t)b * S_ * D_;
    const float* mrow  = mask   + (size_t)b * S_;

    // ET column j, packed in pairs: et2[c] = { exp(T[2c][j]), exp(T[2c+1][j]) }
    f32x2 et2[32];
    #pragma unroll
    for (int c = 0; c < 32; ++c) {
        et2[c].x = __expf(trans[(2 * c + 0) * D_ + j]);
        et2[c].y = __expf(trans[(2 * c + 1) * D_ + j]);
    }

    // single broadcast buffer (one wave per WG: DS pipe is in-order, no barriers)
    __shared__ float4 sp4[16];

    float p  = __expf(yprow[j] * mrow[0]);
    int   K  = 0;      // exact power-of-2 renorm accumulator (offset = K*ln2 + Of)
    float Of = 0.f;    // general masked-path log offset
    ((float*)sp4)[j] = p;

    // one scan step; cs uniform across wave
    auto step = [&](float eraw, float exs, float cs, bool dorescale) {
        const float4* pb = sp4;
        f32x2 a0 = mk2(0.f, 0.f), a1 = a0, a2 = a0, a3 = a0,
              a4 = a0, a5 = a0, a6 = a0, a7 = a0;
        #pragma unroll
        for (int c = 0; c < 16; c += 4) {
            float4 u0 = pb[c], u1 = pb[c + 1], u2 = pb[c + 2], u3 = pb[c + 3];
            a0 = __builtin_elementwise_fma(mk2(u0.x, u0.y), et2[2 * c + 0], a0);
            a1 = __builtin_elementwise_fma(mk2(u0.z, u0.w), et2[2 * c + 1], a1);
            a2 = __builtin_elementwise_fma(mk2(u1.x, u1.y), et2[2 * c + 2], a2);
            a3 = __builtin_elementwise_fma(mk2(u1.z, u1.w), et2[2 * c + 3], a3);
            a4 = __builtin_elementwise_fma(mk2(u2.x, u2.y), et2[2 * c + 4], a4);
            a5 = __builtin_elementwise_fma(mk2(u2.z, u2.w), et2[2 * c + 5], a5);
            a6 = __builtin_elementwise_fma(mk2(u3.x, u3.y), et2[2 * c + 6], a6);
            a7 = __builtin_elementwise_fma(mk2(u3.z, u3.w), et2[2 * c + 7], a7);
        }
        f32x2 s01 = (a0 + a1) + (a2 + a3);
        f32x2 s23 = (a4 + a5) + (a6 + a7);
        f32x2 st  = s01 + s23;
        float sum = st.x + st.y;

        if (cs == 1.0f) {
            p = sum * exs;                       // deferred normalization
        } else {
            // general masked path (exact; rare). ns matches reference exactly:
            // ns = cm*(logsum + e*cm) + (1-cm)*state   (cm^2 == cm for 0/1 mask)
            float sj   = __logf(p);
            float outn = __logf(sum) + eraw * cs;
            float ns   = cs * outn + (1.f - cs) * sj;
            float M = ns;
            #pragma unroll
            for (int m = 1; m <= 32; m <<= 1) M = fmaxf(M, __shfl_xor(M, m, 64));
            p = __expf(ns - M);
            Of += M;
        }
        if (dorescale) {
            // exact power-of-2 rescale: k = exponent of lane0's p (SALU path)
            unsigned pb0 = __builtin_amdgcn_readfirstlane(__float_as_uint(p));
            int k = (int)((pb0 >> 23) & 0xffu) - 127;
            float sc = __uint_as_float((unsigned)(127 - k) << 23);
            p *= sc;                              // exact in fp32
            K += k;
        }
        ((float*)sp4)[j] = p;                     // in-order DS pipe
    };

    // prologue: issue loads for group 0 (t = 1..8)
    float e_nxt[8], c_nxt[8], e_cur[8], c_cur[8], ex[8];
    #pragma unroll
    for (int s = 0; s < 8; ++s) {
        e_nxt[s] = yprow[(size_t)(1 + s) * D_ + j];
        c_nxt[s] = mrow[1 + s];
    }

    // 255 full groups of 8 steps: t = 1 .. 2040
    for (int g = 0; g < 255; ++g) {
        const int tbase = 1 + 8 * g;
        #pragma unroll
        for (int s = 0; s < 8; ++s) { e_cur[s] = e_nxt[s]; c_cur[s] = c_nxt[s]; }
        // issue next group's loads: stay in flight for 8 full steps (~1600 cy)
        #pragma unroll
        for (int s = 0; s < 8; ++s) {
            int t = tbase + 8 + s; if (t > S_ - 1) t = S_ - 1;
            e_nxt[s] = yprow[(size_t)t * D_ + j];
            c_nxt[s] = mrow[t];
        }
        #pragma unroll
        for (int s = 0; s < 8; ++s) ex[s] = __expf(e_cur[s]);
        #pragma unroll
        for (int s = 0; s < 8; ++s)
            step(e_cur[s], ex[s], c_cur[s], (s == 3) || (s == 7));
    }
    // tail: t = 2041..2047 (7 steps), values already in e_nxt[0..6]
    #pragma unroll
    for (int s = 0; s < 7; ++s) ex[s] = __expf(e_nxt[s]);
    #pragma unroll
    for (int s = 0; s < 7; ++s)
        step(e_nxt[s], ex[s], c_nxt[s], (s == 3));

    // logZ = K*ln2 + Of + log(sum_j p_j);  out = logZ - target
    float fs = p;
    #pragma unroll
    for (int m = 1; m <= 32; m <<= 1) fs += __shfl_xor(fs, m, 64);
    if (j == 0) {
        float logz = (float)((double)K * 0.6931471805599453) + Of + __logf(fs);
        out[b] = logz - target[b];
    }
}

extern "C" void kernel_launch(void* const* d_in, const int* in_sizes, int n_in,
                              void* d_out, int out_size, void* d_ws, size_t ws_size,
                              hipStream_t stream)
{
    const float* y_pred = (const float*)d_in[0];
    const int*   y_true = (const int*)d_in[1];
    const float* mask   = (const float*)d_in[2];
    const float* trans  = (const float*)d_in[3];
    float* outp   = (float*)d_out;
    float* target = (float*)d_ws;   // 256 floats of scratch

    hipLaunchKernelGGL(target_kernel, dim3(B_), dim3(256), 0, stream,
                       y_pred, y_true, mask, trans, target);
    hipLaunchKernelGGL(scan_kernel, dim3(B_), dim3(64), 0, stream,
                       y_pred, mask, trans, target, outp);
}